// Round 3
// baseline (618.690 us; speedup 1.0000x reference)
//
#include <hip/hip_runtime.h>

// DSBatchNorm2: per-domain batchnorm (training), D=8, x [65536,1024] f32,
// y [65536] domain ids — harness stages integers as **int32** (round-1
// empirically correct: absmax = 1 bf16 ulp; round-2's int64 2*r read gave
// wrong-grouping error 0.17), gamma/beta [1024] f32.
//
// Strategy: counting-sort row ids by domain (y is 256 KB — trivial), then
// both heavy passes are branch-free streaming over domain-sorted rows:
//   stats: per-wave register accumulation, single atomic flush per wave
//   norm:  scale/bias loaded once per wave, pure load->fma->store
// This kills the per-row branch/dependent-load chains that held round-1
// stats at 9.6% HBM (latency-bound, VALUBusy 13%).

#define NROW  65536
#define NFEAT 1024
#define NF4   256        // float4s per row
#define NDOM  8
#define EPSV  1e-5f

// ws layout in f32 slots (total ~256 KB):
#define WS_SUM   0        // [8][1024] f32
#define WS_SQ    8192     // [8][1024] f32
#define WS_CNT   16384    // u32[8]
#define WS_OFFS  16392    // u32[9]  segment starts (prefix of counts)
#define WS_CUR   16401    // u32[8]  scatter cursors
#define WS_RIDX  16416    // u16[65536] = 32768 f32 slots (16B aligned)
#define WS_SCL   49184    // [8][1024] f32
#define WS_BIA   57376    // [8][1024] f32
#define WS_ZERO_BYTES ((16384 + 8) * 4)   // gsum+gsq+gcnt

__global__ __launch_bounds__(256) void dsbn_hist(
    const int* __restrict__ y, unsigned* __restrict__ gcnt)
{
  __shared__ unsigned lh[NDOM];
  const int tid = threadIdx.x;
  if (tid < NDOM) lh[tid] = 0u;
  __syncthreads();
  const int r = blockIdx.x * 256 + tid;
  const int d = y[r] & 7;
  atomicAdd(&lh[d], 1u);
  __syncthreads();
  if (tid < NDOM) atomicAdd(&gcnt[tid], lh[tid]);
}

__global__ void dsbn_scan(const unsigned* __restrict__ gcnt,
                          unsigned* __restrict__ offs,
                          unsigned* __restrict__ cursor)
{
  if (threadIdx.x == 0) {
    unsigned c = 0;
    for (int d = 0; d < NDOM; ++d) { offs[d] = c; cursor[d] = c; c += gcnt[d]; }
    offs[NDOM] = c;
  }
}

__global__ __launch_bounds__(256) void dsbn_scatter(
    const int* __restrict__ y, unsigned* __restrict__ cursor,
    unsigned short* __restrict__ ridx)
{
  __shared__ unsigned lh[NDOM], lbase[NDOM];
  const int tid = threadIdx.x;
  if (tid < NDOM) lh[tid] = 0u;
  __syncthreads();
  const int r = blockIdx.x * 256 + tid;
  const int d = y[r] & 7;
  const unsigned rank = atomicAdd(&lh[d], 1u);
  __syncthreads();
  if (tid < NDOM) lbase[tid] = atomicAdd(&cursor[tid], lh[tid]);
  __syncthreads();
  ridx[lbase[d] + rank] = (unsigned short)r;
}

// wave decomposition shared by stats/norm:
//   gw = blockIdx*4 + wave; chunk = gw>>2 (32 sorted rows); ftile = gw&3
__global__ __launch_bounds__(256) void dsbn_stats(
    const float* __restrict__ x, const unsigned short* __restrict__ ridx,
    const unsigned* __restrict__ offs,
    float* __restrict__ gsum, float* __restrict__ gsq)
{
  const int tid   = threadIdx.x;
  const int w     = tid >> 6, lane = tid & 63;
  const int gw    = blockIdx.x * 4 + w;
  const int chunk = gw >> 2;
  const int ftile = gw & 3;
  const int c4    = ftile * 64 + lane;
  const int p0    = chunk * 32;

  const int myr = (int)ridx[p0 + (lane & 31)];   // rows of this chunk, in lanes

  int d0 = 0;
#pragma unroll
  for (int k = 1; k < NDOM; ++k) d0 += (p0 >= (int)offs[k]) ? 1 : 0;
  const bool single = (p0 + 32 <= (int)offs[d0 + 1]);

  const float4* __restrict__ x4 = reinterpret_cast<const float4*>(x);
  float4 s = make_float4(0.f, 0.f, 0.f, 0.f);
  float4 q = make_float4(0.f, 0.f, 0.f, 0.f);

  auto flush = [&](int dd) {
    float* gs = gsum + dd * NFEAT + c4 * 4;
    float* gq = gsq  + dd * NFEAT + c4 * 4;
    atomicAdd(gs + 0, s.x); atomicAdd(gs + 1, s.y);
    atomicAdd(gs + 2, s.z); atomicAdd(gs + 3, s.w);
    atomicAdd(gq + 0, q.x); atomicAdd(gq + 1, q.y);
    atomicAdd(gq + 2, q.z); atomicAdd(gq + 3, q.w);
  };

  if (single) {
    // hot path: branch-free, scalar row base -> saddr loads, pipelineable
#pragma unroll 4
    for (int k = 0; k < 32; ++k) {
      const int r = (int)__builtin_amdgcn_readlane((unsigned)myr, (unsigned)k);
      const float4 v = x4[(size_t)r * NF4 + c4];
      s.x += v.x; s.y += v.y; s.z += v.z; s.w += v.w;
      q.x = fmaf(v.x, v.x, q.x); q.y = fmaf(v.y, v.y, q.y);
      q.z = fmaf(v.z, v.z, q.z); q.w = fmaf(v.w, v.w, q.w);
    }
    flush(d0);
  } else {
    // cold path: <=28 waves total cross a domain boundary
    int d = d0;
    for (int k = 0; k < 32; ++k) {
      const int p = p0 + k;
      const int r = (int)__builtin_amdgcn_readlane((unsigned)myr, (unsigned)k);
      while (p >= (int)offs[d + 1]) {
        flush(d);
        s = make_float4(0.f, 0.f, 0.f, 0.f);
        q = make_float4(0.f, 0.f, 0.f, 0.f);
        ++d;
      }
      const float4 v = x4[(size_t)r * NF4 + c4];
      s.x += v.x; s.y += v.y; s.z += v.z; s.w += v.w;
      q.x = fmaf(v.x, v.x, q.x); q.y = fmaf(v.y, v.y, q.y);
      q.z = fmaf(v.z, v.z, q.z); q.w = fmaf(v.w, v.w, q.w);
    }
    flush(d);
  }
}

__global__ __launch_bounds__(256) void dsbn_prep(
    const float* __restrict__ gsum, const float* __restrict__ gsq,
    const unsigned* __restrict__ gcnt,
    const float* __restrict__ gamma, const float* __restrict__ beta,
    float* __restrict__ scl, float* __restrict__ bia)
{
  const int i = blockIdx.x * 256 + threadIdx.x;   // 0..8191
  const int d = i >> 10;
  const int f = i & 1023;
  const float c    = (float)gcnt[d];
  const float sc   = fmaxf(c, 1.f);
  const float mean = gsum[i] / sc;
  float var = gsq[i] / sc - mean * mean;   // E[x^2]-mean^2
  var = fmaxf(var, 0.f);
  float scale, bias;
  if (c > 1.5f) {
    const float inv = 1.f / sqrtf(var + EPSV);
    scale = gamma[f] * inv;
    bias  = fmaf(-mean, scale, beta[f]);
  } else if (c > 0.5f) {   // count == 1 -> raw x
    scale = 1.f; bias = 0.f;
  } else {                 // count == 0 -> 0
    scale = 0.f; bias = 0.f;
  }
  scl[i] = scale;
  bia[i] = bias;
}

__global__ __launch_bounds__(256) void dsbn_norm(
    const float* __restrict__ x, const unsigned short* __restrict__ ridx,
    const unsigned* __restrict__ offs,
    const float* __restrict__ scl, const float* __restrict__ bia,
    float* __restrict__ out)
{
  const int tid   = threadIdx.x;
  const int w     = tid >> 6, lane = tid & 63;
  const int gw    = blockIdx.x * 4 + w;
  const int chunk = gw >> 2;
  const int ftile = gw & 3;
  const int c4    = ftile * 64 + lane;
  const int p0    = chunk * 32;

  const int myr = (int)ridx[p0 + (lane & 31)];

  int d0 = 0;
#pragma unroll
  for (int k = 1; k < NDOM; ++k) d0 += (p0 >= (int)offs[k]) ? 1 : 0;
  const bool single = (p0 + 32 <= (int)offs[d0 + 1]);

  const float4* __restrict__ x4 = reinterpret_cast<const float4*>(x);
  const float4* __restrict__ s4 = reinterpret_cast<const float4*>(scl);
  const float4* __restrict__ b4 = reinterpret_cast<const float4*>(bia);
  float4* __restrict__ o4 = reinterpret_cast<float4*>(out);

  if (single) {
    const float4 sc = s4[d0 * NF4 + c4];   // loaded ONCE per wave
    const float4 bb = b4[d0 * NF4 + c4];
#pragma unroll 4
    for (int k = 0; k < 32; ++k) {
      const int r = (int)__builtin_amdgcn_readlane((unsigned)myr, (unsigned)k);
      const float4 v = x4[(size_t)r * NF4 + c4];
      float4 o;
      o.x = fmaf(v.x, sc.x, bb.x);
      o.y = fmaf(v.y, sc.y, bb.y);
      o.z = fmaf(v.z, sc.z, bb.z);
      o.w = fmaf(v.w, sc.w, bb.w);
      o4[(size_t)r * NF4 + c4] = o;
    }
  } else {
    int d = d0;
    for (int k = 0; k < 32; ++k) {
      const int p = p0 + k;
      const int r = (int)__builtin_amdgcn_readlane((unsigned)myr, (unsigned)k);
      while (p >= (int)offs[d + 1]) ++d;
      const float4 sc = s4[d * NF4 + c4];
      const float4 bb = b4[d * NF4 + c4];
      const float4 v = x4[(size_t)r * NF4 + c4];
      float4 o;
      o.x = fmaf(v.x, sc.x, bb.x);
      o.y = fmaf(v.y, sc.y, bb.y);
      o.z = fmaf(v.z, sc.z, bb.z);
      o.w = fmaf(v.w, sc.w, bb.w);
      o4[(size_t)r * NF4 + c4] = o;
    }
  }
}

extern "C" void kernel_launch(void* const* d_in, const int* in_sizes, int n_in,
                              void* d_out, int out_size, void* d_ws, size_t ws_size,
                              hipStream_t stream) {
  const float* x     = (const float*)d_in[0];
  const int*   y     = (const int*)  d_in[1];   // int32 (harness-converted)
  const float* gamma = (const float*)d_in[2];
  const float* beta  = (const float*)d_in[3];
  float* out = (float*)d_out;

  float*          ws     = (float*)d_ws;
  float*          gsum   = ws + WS_SUM;
  float*          gsq    = ws + WS_SQ;
  unsigned*       gcnt   = (unsigned*)(ws + WS_CNT);
  unsigned*       offs   = (unsigned*)(ws + WS_OFFS);
  unsigned*       cursor = (unsigned*)(ws + WS_CUR);
  unsigned short* ridx   = (unsigned short*)(ws + WS_RIDX);
  float*          scl    = ws + WS_SCL;
  float*          bia    = ws + WS_BIA;

  // ws is re-poisoned to 0xAA before every timed call -> zero accumulators
  hipMemsetAsync(ws, 0, WS_ZERO_BYTES, stream);

  dsbn_hist   <<<dim3(256),  dim3(256), 0, stream>>>(y, gcnt);
  dsbn_scan   <<<dim3(1),    dim3(64),  0, stream>>>(gcnt, offs, cursor);
  dsbn_scatter<<<dim3(256),  dim3(256), 0, stream>>>(y, cursor, ridx);
  dsbn_stats  <<<dim3(2048), dim3(256), 0, stream>>>(x, ridx, offs, gsum, gsq);
  dsbn_prep   <<<dim3(32),   dim3(256), 0, stream>>>(gsum, gsq, gcnt, gamma, beta, scl, bia);
  dsbn_norm   <<<dim3(2048), dim3(256), 0, stream>>>(x, ridx, offs, scl, bia, out);
}